// Round 1
// baseline (694.379 us; speedup 1.0000x reference)
//
#include <hip/hip_runtime.h>
#include <math.h>

// CPDist: B=8, T=128, D=1024, V=4096, R=16, H=2
// outputs: p_eval[8], norm_const[8]
//
// norm_const[b] = sum_r S[b][0][r]*S[b][1][r],  S[b][h][r] = sum_v exp(dot+bias)
// p_eval[b]    = sum_r E[b][0][r]*E[b][1][r],  E[b][h][r] = exp value at v=points[b][h]
//
// Roofline: param_w = 512 MB fp32 read once from HBM -> ~82 us at 6.3 TB/s.
//
// ROUND 1 RESTRUCTURE: contiguous streaming. Prior version gave each wave a
// fixed (h,r) and strided v (4 KB reads at 64 KB stride, 2048 interleaved
// streams) -> 762 GB/s effective. Now each wave owns 64 CONSECUTIVE rows
// (256 KB contiguous); a 256-thread block owns 1 MB contiguous. Consecutive
// rows cycle r=0..15, so we keep 16 per-r accumulators in registers with
// compile-time indices (inner 16-row group fully unrolled).
//
// ws layout (floats):
//   [0 .. 65536)        S_part[blk][slot]  blk=512, slot = b*16+r  (coalesced)
//   [65536 .. 65792)    E[b][h][r]         (unconditional unique writer)
// No zero-init needed anywhere -> no init kernel, no atomics.

#define B_ 8
#define T_ 128
#define D_ 1024
#define V_ 4096
#define R_ 16
#define H_ 2

#define EOFF 65536

// Folded reduce: 8 values over 64 lanes -> lane l holds total for b=bitrev3(l&7).
__device__ __forceinline__ float folded_reduce8(const float* p, int lane) {
    float t[4];
    {
        const bool hi = lane & 1;
#pragma unroll
        for (int i = 0; i < 4; ++i) {
            float send = hi ? p[i] : p[i + 4];
            float recv = __shfl_xor(send, 1);
            float keep = hi ? p[i + 4] : p[i];
            t[i] = keep + recv;
        }
    }
    float u[2];
    {
        const bool hi = lane & 2;
#pragma unroll
        for (int i = 0; i < 2; ++i) {
            float send = hi ? t[i] : t[i + 2];
            float recv = __shfl_xor(send, 2);
            float keep = hi ? t[i + 2] : t[i];
            u[i] = keep + recv;
        }
    }
    float wv;
    {
        const bool hi = lane & 4;
        float send = hi ? u[0] : u[1];
        float recv = __shfl_xor(send, 4);
        float keep = hi ? u[1] : u[0];
        wv = keep + recv;
    }
    wv += __shfl_xor(wv, 8);
    wv += __shfl_xor(wv, 16);
    wv += __shfl_xor(wv, 32);
    return wv;
}

__device__ __forceinline__ void row_partials(const float4* __restrict__ Wr,
                                             const float4 hreg[8][4], float* p) {
#pragma unroll
    for (int b = 0; b < 8; ++b) {
        float s = 0.0f;
#pragma unroll
        for (int j = 0; j < 4; ++j) {
            s = fmaf(Wr[j].x, hreg[b][j].x, s);
            s = fmaf(Wr[j].y, hreg[b][j].y, s);
            s = fmaf(Wr[j].z, hreg[b][j].z, s);
            s = fmaf(Wr[j].w, hreg[b][j].w, s);
        }
        p[b] = s;
    }
}

// grid: 512 blocks x 256 threads (4 waves). Block owns 256 consecutive rows
// (1 MB contiguous); wave w owns rows [256*blk + 64*w, +64) = 256 KB contiguous.
// h = blk>>8 (65536 rows per h, block never straddles). Row g in h:
// v = g>>4, r = g&15 -- one v per 16-row group, r == static unroll index.
// Ping-pong A/B register buffers, NO copies: per-register waitcnt leaves the
// other buffer's loads in flight across every wait.
__global__ __launch_bounds__(256, 2) void cpdist_main(
    const float* __restrict__ hid,    // B*T*D
    const float* __restrict__ W,      // (V*R*H) x D
    const float* __restrict__ bias,   // V*R*H
    const int*   __restrict__ points, // B*H
    float* __restrict__ ws)
{
    const int tid  = threadIdx.x;
    const int lane = tid & 63;
    const int wave = tid >> 6;
    const int blk  = blockIdx.x;          // 0..511
    const int h    = blk >> 8;            // 0..1
    const size_t rowBase = (size_t)blk * 256 + (size_t)wave * 64;
    const int vBase = (int)((rowBase & 65535u) >> 4);   // v of first 16-row group

    // after the folded reduce, lane l holds the sum for b = bitrev3(l&7)
    const int myb = ((lane & 1) << 2) | (lane & 2) | ((lane >> 2) & 1);

    // h_last fragments in registers: hreg[b][j] = h_last[b][j*256 + lane*4 .. +3]
    float4 hreg[8][4];
#pragma unroll
    for (int b = 0; b < 8; ++b) {
        const float* hb = hid + ((size_t)b * T_ + (T_ - 1)) * D_;
#pragma unroll
        for (int j = 0; j < 4; ++j)
            hreg[b][j] = *reinterpret_cast<const float4*>(hb + j * 256 + lane * 4);
    }

    const int pv = points[myb * H_ + h];   // v selected by (myb, h)

    const float* wp = W + rowBase * D_;    // contiguous 256 KB from here
    const float* bp = bias + rowBase;

    // preload rows 0 (A) and 1 (B)
    float4 A[4], Bf[4];
#pragma unroll
    for (int j = 0; j < 4; ++j) {
        A[j]  = *reinterpret_cast<const float4*>(wp + j * 256 + lane * 4);
        Bf[j] = *reinterpret_cast<const float4*>(wp + D_ + j * 256 + lane * 4);
    }

    float accR[16];
#pragma unroll
    for (int i = 0; i < 16; ++i) accR[i] = 0.0f;

#pragma unroll 1
    for (int it0 = 0; it0 < 64; it0 += 16) {
        const int  vCur = vBase + (it0 >> 4);
        const bool ev   = (vCur == pv) && (lane < 8);

#pragma unroll
        for (int k = 0; k < 16; k += 2) {
            const int it = it0 + k;
            const float biasA = bp[it];
            const float biasB = bp[it + 1];

            // ---- compute row it from A (waits only on A's 4 loads) ----
            float p[8];
            row_partials(A, hreg, p);
            const float wvA = folded_reduce8(p, lane);

            // reissue A <- row it+2 (B's loads + these stay in flight)
            if (k < 14 || it0 < 48) {
                const float* wn = wp + (size_t)(it + 2) * D_;
#pragma unroll
                for (int j = 0; j < 4; ++j)
                    A[j] = *reinterpret_cast<const float4*>(wn + j * 256 + lane * 4);
            }

            // ---- compute row it+1 from B ----
            row_partials(Bf, hreg, p);
            const float wvB = folded_reduce8(p, lane);

            // reissue B <- row it+3
            if (k < 14 || it0 < 48) {
                const float* wn = wp + (size_t)(it + 3) * D_;
#pragma unroll
                for (int j = 0; j < 4; ++j)
                    Bf[j] = *reinterpret_cast<const float4*>(wn + j * 256 + lane * 4);
            }

            const float valA = __expf(wvA + biasA);
            const float valB = __expf(wvB + biasB);
            accR[k]     += valA;   // r == k   (rowBase multiple of 16)
            accR[k + 1] += valB;   // r == k+1

            if (ev) {   // unique writer per E slot: exactly one 16-row group matches
                ws[EOFF + (myb * H_ + h) * R_ + k]     = valA;
                ws[EOFF + (myb * H_ + h) * R_ + k + 1] = valB;
            }
        }
    }

    // cross-wave reduce of S partials, then one coalesced 128-float store/block
    __shared__ float sred[4][128];
    if (lane < 8) {
#pragma unroll
        for (int rr = 0; rr < 16; ++rr)
            sred[wave][myb * 16 + rr] = accR[rr];
    }
    __syncthreads();
    if (tid < 128) {
        const float s = sred[0][tid] + sred[1][tid] + sred[2][tid] + sred[3][tid];
        ws[(size_t)blk * 128 + tid] = s;   // slot = b*16 + r
    }
}

// 256 threads: t -> b = t>>5, h = (t>>4)&1, r = t&15.
// S[b][h][r] = sum over the 256 blocks of h at stride 128.
__global__ void cpdist_finalize(const float* __restrict__ ws, float* __restrict__ out) {
    const int t = threadIdx.x;
    const int b = t >> 5;
    const int h = (t >> 4) & 1;
    const int r = t & 15;

    const float* sp = ws + (size_t)h * 256 * 128 + (b * 16 + r);
    float S = 0.0f;
#pragma unroll 8
    for (int bi = 0; bi < 256; ++bi)
        S += sp[(size_t)bi * 128];

    const float E = ws[EOFF + (b * 2 + h) * 16 + r];

    const float So = __shfl_xor(S, 16);
    const float Eo = __shfl_xor(E, 16);
    float nc = S * So;   // S[b][0][r] * S[b][1][r] (both h-lanes compute it)
    float pe = E * Eo;
#pragma unroll
    for (int m = 1; m < 16; m <<= 1) {
        nc += __shfl_xor(nc, m);
        pe += __shfl_xor(pe, m);
    }
    if ((t & 31) == 0) {
        out[b] = pe;        // p_eval
        out[8 + b] = nc;    // norm_const
    }
}

extern "C" void kernel_launch(void* const* d_in, const int* in_sizes, int n_in,
                              void* d_out, int out_size, void* d_ws, size_t ws_size,
                              hipStream_t stream) {
    const float* hid    = (const float*)d_in[0];   // last_hidden_state
    const float* W      = (const float*)d_in[1];   // param_w
    const float* bias   = (const float*)d_in[2];   // param_b
    const int*   points = (const int*)d_in[3];     // points
    float* out = (float*)d_out;
    float* ws  = (float*)d_ws;

    hipLaunchKernelGGL(cpdist_main, dim3(512), dim3(256), 0, stream,
                       hid, W, bias, points, ws);
    hipLaunchKernelGGL(cpdist_finalize, dim3(1), dim3(256), 0, stream, ws, out);
}